// Round 7
// baseline (856.063 us; speedup 1.0000x reference)
//
#include <hip/hip_runtime.h>
#include <hip/hip_bf16.h>
#include <math.h>

#define NN 50000
#define NE 1600000
#define D 128
#define NRBF 50
#define RCUT 5.0f
#define LNEPS 1e-5f
#define EB 16
#define EB2 64
#define EDGE_GRID 2048
#define SCAN_B 196   // ceil(50000/256)
#define NB 16
#define NPB 8        // nodes per block in gather

typedef __attribute__((ext_vector_type(8))) short bf16x8;
typedef __attribute__((ext_vector_type(4))) float f32x4;

__device__ __forceinline__ float silu_f(float x) {
    return x / (1.0f + __expf(-x));
}
__device__ __forceinline__ unsigned short f2bf(float x) {
    __hip_bfloat16 b = __float2bfloat16(x);
    return *reinterpret_cast<unsigned short*>(&b);
}
__device__ __forceinline__ float bf2f(unsigned short u) {
    unsigned int x = ((unsigned int)u) << 16;
    return __uint_as_float(x);
}

// ---------------------------------------------------------------- nbr
__global__ __launch_bounds__(128) void nbr_kernel(
    const float* __restrict__ z, const float* __restrict__ Aw,
    const float* __restrict__ Ab, unsigned short* __restrict__ nbr_bf)
{
    const int n = blockIdx.x;
    const int d = threadIdx.x;
    float acc = Ab[d];
#pragma unroll
    for (int k = 0; k < 25; ++k)
        acc = fmaf(z[n * 25 + k], Aw[k * D + d], acc);
    nbr_bf[(size_t)n * D + d] = f2bf(silu_f(acc));
}

// ---------------------------------------------------------------- count
__global__ __launch_bounds__(256) void count_kernel(
    const int* __restrict__ edge, int* __restrict__ cnt)
{
    const int e = blockIdx.x * 256 + threadIdx.x;
    if (e >= NE) return;
    atomicAdd(&cnt[edge[2 * e]], 1);
}

// ---------------------------------------------------------------- scans
__global__ __launch_bounds__(256) void scan1_kernel(
    const int* __restrict__ cnt, int* __restrict__ off, int* __restrict__ bsum)
{
    __shared__ int s[2][256];
    const int t = threadIdx.x;
    const int g = blockIdx.x * 256 + t;
    const int v = (g < NN) ? cnt[g] : 0;
    int incl = v;
    s[0][t] = incl;
    __syncthreads();
    int cur = 0;
#pragma unroll
    for (int dd = 1; dd < 256; dd <<= 1) {
        const int add = (t >= dd) ? s[cur][t - dd] : 0;
        incl += add;
        s[cur ^ 1][t] = incl;
        __syncthreads();
        cur ^= 1;
    }
    if (g < NN) off[g] = incl - v;
    if (t == 255) bsum[blockIdx.x] = incl;
}

__global__ __launch_bounds__(256) void scan2_kernel(int* __restrict__ bsum)
{
    __shared__ int s[2][256];
    const int t = threadIdx.x;
    const int v = (t < SCAN_B) ? bsum[t] : 0;
    int incl = v;
    s[0][t] = incl;
    __syncthreads();
    int cur = 0;
#pragma unroll
    for (int dd = 1; dd < 256; dd <<= 1) {
        const int add = (t >= dd) ? s[cur][t - dd] : 0;
        incl += add;
        s[cur ^ 1][t] = incl;
        __syncthreads();
        cur ^= 1;
    }
    if (t < SCAN_B) bsum[t] = incl - v;
}

__global__ __launch_bounds__(256) void scan3_kernel(
    int* __restrict__ off, const int* __restrict__ bsum)
{
    const int g = blockIdx.x * 256 + threadIdx.x;
    if (g < NN) off[g] += bsum[blockIdx.x];
    if (g == 0) off[NN] = NE;
}

// ---------------------------------------------------------------- scatter
// packed slot per CSR position: {j, r_bits, e, i}
__global__ __launch_bounds__(256) void scatter_kernel(
    const int* __restrict__ edge, const float* __restrict__ r,
    const int* __restrict__ off, int* __restrict__ cursor,
    uint4* __restrict__ slots)
{
    const int e = blockIdx.x * 256 + threadIdx.x;
    if (e >= NE) return;
    const int2 ep = ((const int2*)edge)[e];
    const int pos = atomicAdd(&cursor[ep.x], 1);
    slots[off[ep.x] + pos] =
        make_uint4((unsigned int)ep.y, __float_as_uint(r[e]),
                   (unsigned int)e, (unsigned int)ep.x);
}

// ---------------------------------------------------------------- gather msg (MFMA)
// col map: col = w*64 + lr*4 + dt
__global__ __launch_bounds__(128) void gather_msg_mfma(
    const uint4* __restrict__ slots, const int* __restrict__ off,
    const float* __restrict__ W_ndp, const float* __restrict__ b_ndp,
    const unsigned short* __restrict__ nbr_bf, float* __restrict__ m)
{
    __shared__ unsigned short P[EB][64];
    __shared__ float er_s[EB];
    __shared__ float c_s[EB];
    __shared__ int   j_s[EB];

    const int tid = threadIdx.x;
    const int w   = tid >> 6;
    const int l   = tid & 63;
    const int lr  = l & 15;
    const int lg  = l >> 4;

    bf16x8 wf[4][2];
#pragma unroll
    for (int dt = 0; dt < 4; ++dt) {
        const int col = w * 64 + lr * 4 + dt;
#pragma unroll
        for (int s = 0; s < 2; ++s) {
            bf16x8 v;
#pragma unroll
            for (int j = 0; j < 8; ++j) {
                const int k = s * 32 + lg * 8 + j;
                float wv = 0.0f;
                if (k < NRBF)       wv = W_ndp[k * D + col];
                else if (k == NRBF) wv = b_ndp[col];
                v[j] = (short)f2bf(wv);
            }
            wf[dt][s] = v;
        }
    }

    const float start = expf(-RCUT);
    const float step  = (1.0f - start) / (NRBF - 1);
    const float bq    = (2.0f / NRBF) * (1.0f - start);
    const float beta  = 1.0f / (bq * bq);

    const int prow = tid >> 3;
    const int pci  = tid & 7;

    for (int nn = 0; nn < NPB; ++nn) {
        const int n   = blockIdx.x * NPB + nn;
        const int s0  = off[n];
        const int deg = off[n + 1] - s0;

        f32x4 macc[4] = {{0,0,0,0},{0,0,0,0},{0,0,0,0},{0,0,0,0}};

        for (int base = 0; base < deg; base += EB) {
            const int chunk = min(EB, deg - base);
            if (tid < EB) {
                if (tid < chunk) {
                    const uint4 v = slots[s0 + base + tid];   // contiguous
                    const float rr = __uint_as_float(v.y);
                    er_s[tid] = __expf(-rr);
                    c_s[tid] = (rr < RCUT)
                        ? 0.5f * (__cosf(3.14159265358979f * rr * (1.0f / RCUT)) + 1.0f)
                        : 0.0f;
                    j_s[tid] = (int)v.x;
                } else {
                    er_s[tid] = 0.0f; c_s[tid] = 0.0f; j_s[tid] = 0;
                }
            }
            __syncthreads();
            {
                const float er = er_s[prow];
                const float cc = c_s[prow];
                unsigned int pk[4];
#pragma unroll
                for (int p2 = 0; p2 < 4; ++p2) {
                    unsigned int word = 0;
#pragma unroll
                    for (int c = 0; c < 2; ++c) {
                        const int k = pci * 8 + p2 * 2 + c;
                        float v = 0.0f;
                        if (k < NRBF) {
                            const float diff = er - (start + (float)k * step);
                            v = cc * __expf(-beta * diff * diff);
                        } else if (k == NRBF) {
                            v = cc;
                        }
                        word |= ((unsigned int)f2bf(v)) << (16 * c);
                    }
                    pk[p2] = word;
                }
                const int swc = pci ^ (prow & 7);
                *(uint4*)&P[prow][swc * 8] = make_uint4(pk[0], pk[1], pk[2], pk[3]);
            }
            __syncthreads();
            bf16x8 af[2];
#pragma unroll
            for (int s = 0; s < 2; ++s) {
                const int swc = (s * 4 + lg) ^ (lr & 7);
                af[s] = *(const bf16x8*)&P[lr][swc * 8];
            }
            f32x4 accs[4];
#pragma unroll
            for (int dt = 0; dt < 4; ++dt) {
                f32x4 acc = {0.0f, 0.0f, 0.0f, 0.0f};
                acc = __builtin_amdgcn_mfma_f32_16x16x32_bf16(af[0], wf[dt][0], acc, 0, 0, 0);
                acc = __builtin_amdgcn_mfma_f32_16x16x32_bf16(af[1], wf[dt][1], acc, 0, 0, 0);
                accs[dt] = acc;
            }
#pragma unroll
            for (int q = 0; q < 4; ++q) {
                const int row = j_s[lg * 4 + q];
                const uint2 nv8 = *(const uint2*)(nbr_bf + (size_t)row * D + w * 64 + lr * 4);
                const float n0 = bf2f((unsigned short)(nv8.x & 0xffff));
                const float n1 = bf2f((unsigned short)(nv8.x >> 16));
                const float n2 = bf2f((unsigned short)(nv8.y & 0xffff));
                const float n3 = bf2f((unsigned short)(nv8.y >> 16));
                macc[0][q] = fmaf(n0, accs[0][q], macc[0][q]);
                macc[1][q] = fmaf(n1, accs[1][q], macc[1][q]);
                macc[2][q] = fmaf(n2, accs[2][q], macc[2][q]);
                macc[3][q] = fmaf(n3, accs[3][q], macc[3][q]);
            }
            __syncthreads();
        }

        float v0 = macc[0][0] + macc[0][1] + macc[0][2] + macc[0][3];
        float v1 = macc[1][0] + macc[1][1] + macc[1][2] + macc[1][3];
        float v2 = macc[2][0] + macc[2][1] + macc[2][2] + macc[2][3];
        float v3 = macc[3][0] + macc[3][1] + macc[3][2] + macc[3][3];
        v0 += __shfl_xor(v0, 16); v0 += __shfl_xor(v0, 32);
        v1 += __shfl_xor(v1, 16); v1 += __shfl_xor(v1, 32);
        v2 += __shfl_xor(v2, 16); v2 += __shfl_xor(v2, 32);
        v3 += __shfl_xor(v3, 16); v3 += __shfl_xor(v3, 32);
        if (lg == 0) {
            float4 o = {v0, v1, v2, v3};
            *(float4*)&m[(size_t)n * D + w * 64 + lr * 4] = o;
        }
    }
}

// ---------------------------------------------------------------- node MLP
__global__ __launch_bounds__(256) void node_kernel2(
    const float* __restrict__ z, const float* __restrict__ A_na_w,
    const float* __restrict__ A_na_b, const float* __restrict__ m,
    const float* __restrict__ W_nrd_w, const float* __restrict__ W_nrd_b,
    const float* __restrict__ W_nru_w, const float* __restrict__ W_nru_b,
    const float* __restrict__ ln_g, const float* __restrict__ ln_b,
    float* __restrict__ hout, unsigned short* __restrict__ h_bf)
{
    __shared__ float inbuf[NB][260];
    __shared__ float wbuf[32][128];
    __shared__ float part[4][NB][2];

    const int tid = threadIdx.x;
    const int n0 = blockIdx.x * NB;
    const int nl = tid & 15;
    const int dg = tid >> 4;

    for (int idx = tid; idx < NB * 128; idx += 256) {
        const int n = idx >> 7;
        const int d = idx & 127;
        float acc = A_na_b[d];
#pragma unroll
        for (int k = 0; k < 25; ++k)
            acc = fmaf(z[(size_t)(n0 + n) * 25 + k], A_na_w[k * D + d], acc);
        inbuf[n][d]       = silu_f(acc);
        inbuf[n][128 + d] = m[(size_t)(n0 + n) * D + d];
    }

    float h1[8];
#pragma unroll
    for (int dd = 0; dd < 8; ++dd) h1[dd] = W_nrd_b[dg * 8 + dd];

    for (int tile = 0; tile < 8; ++tile) {
        __syncthreads();
        for (int v = tid; v < 32 * 32; v += 256) {
            const int row = v >> 5;
            const int c4  = (v & 31) * 4;
            *(float4*)&wbuf[row][c4] =
                *(const float4*)&W_nrd_w[(size_t)(tile * 32 + row) * D + c4];
        }
        __syncthreads();
#pragma unroll 4
        for (int k = 0; k < 32; ++k) {
            const float rin = inbuf[nl][tile * 32 + k];
            const float4 wa = *(const float4*)&wbuf[k][dg * 8];
            const float4 wb = *(const float4*)&wbuf[k][dg * 8 + 4];
            h1[0] = fmaf(rin, wa.x, h1[0]);
            h1[1] = fmaf(rin, wa.y, h1[1]);
            h1[2] = fmaf(rin, wa.z, h1[2]);
            h1[3] = fmaf(rin, wa.w, h1[3]);
            h1[4] = fmaf(rin, wb.x, h1[4]);
            h1[5] = fmaf(rin, wb.y, h1[5]);
            h1[6] = fmaf(rin, wb.z, h1[6]);
            h1[7] = fmaf(rin, wb.w, h1[7]);
        }
    }

    float s = 0.0f, sq = 0.0f;
#pragma unroll
    for (int dd = 0; dd < 8; ++dd) { s += h1[dd]; sq += h1[dd] * h1[dd]; }
    s  += __shfl_xor(s, 16);  sq += __shfl_xor(sq, 16);
    s  += __shfl_xor(s, 32);  sq += __shfl_xor(sq, 32);
    const int wv = tid >> 6;
    if ((tid & 63) < 16) { part[wv][nl][0] = s; part[wv][nl][1] = sq; }
    __syncthreads();
    float ts = 0.0f, tsq = 0.0f;
#pragma unroll
    for (int w = 0; w < 4; ++w) { ts += part[w][nl][0]; tsq += part[w][nl][1]; }
    const float mu  = ts * (1.0f / 128.0f);
    const float var = tsq * (1.0f / 128.0f) - mu * mu;
    const float inv = rsqrtf(var + LNEPS);

#pragma unroll
    for (int dd = 0; dd < 8; ++dd) {
        const int d = dg * 8 + dd;
        inbuf[nl][d] = silu_f((h1[dd] - mu) * inv * ln_g[d] + ln_b[d]);
    }

    float h2[8];
#pragma unroll
    for (int dd = 0; dd < 8; ++dd) h2[dd] = W_nru_b[dg * 8 + dd];

    for (int tile = 0; tile < 4; ++tile) {
        __syncthreads();
        for (int v = tid; v < 32 * 32; v += 256) {
            const int row = v >> 5;
            const int c4  = (v & 31) * 4;
            *(float4*)&wbuf[row][c4] =
                *(const float4*)&W_nru_w[(size_t)(tile * 32 + row) * D + c4];
        }
        __syncthreads();
#pragma unroll 4
        for (int k = 0; k < 32; ++k) {
            const float rin = inbuf[nl][tile * 32 + k];
            const float4 wa = *(const float4*)&wbuf[k][dg * 8];
            const float4 wb = *(const float4*)&wbuf[k][dg * 8 + 4];
            h2[0] = fmaf(rin, wa.x, h2[0]);
            h2[1] = fmaf(rin, wa.y, h2[1]);
            h2[2] = fmaf(rin, wa.z, h2[2]);
            h2[3] = fmaf(rin, wa.w, h2[3]);
            h2[4] = fmaf(rin, wb.x, h2[4]);
            h2[5] = fmaf(rin, wb.y, h2[5]);
            h2[6] = fmaf(rin, wb.z, h2[6]);
            h2[7] = fmaf(rin, wb.w, h2[7]);
        }
    }

    float4 o0 = {h2[0], h2[1], h2[2], h2[3]};
    float4 o1 = {h2[4], h2[5], h2[6], h2[7]};
    *(float4*)&hout[(size_t)(n0 + nl) * D + dg * 8]     = o0;
    *(float4*)&hout[(size_t)(n0 + nl) * D + dg * 8 + 4] = o1;

    unsigned int b0 = (unsigned int)f2bf(h2[0]) | ((unsigned int)f2bf(h2[1]) << 16);
    unsigned int b1 = (unsigned int)f2bf(h2[2]) | ((unsigned int)f2bf(h2[3]) << 16);
    unsigned int b2 = (unsigned int)f2bf(h2[4]) | ((unsigned int)f2bf(h2[5]) << 16);
    unsigned int b3 = (unsigned int)f2bf(h2[6]) | ((unsigned int)f2bf(h2[7]) << 16);
    *(uint4*)&h_bf[(size_t)(n0 + nl) * D + dg * 8] = make_uint4(b0, b1, b2, b3);
}

// ---------------------------------------------------------------- edge out (MFMA, CSR order)
// Iterates i-sorted CSR slots: h_bf[i] hits L1/L2 (few distinct i per chunk);
// only h_bf[j] stays random. t written scattered by e (512B rows).
// col map: col = lr*8 + dt.
__global__ __launch_bounds__(256) void edge_out_mfma(
    const uint4* __restrict__ slots, const float* __restrict__ W_erp,
    const float* __restrict__ b_erp, const unsigned short* __restrict__ h_bf,
    float* __restrict__ t)
{
    __shared__ unsigned short P[EB2][64];       // 8 KB
    __shared__ unsigned short hv[EB2][136];     // 17.4 KB
    __shared__ int ij_s[EB2][2];
    __shared__ int e_s[EB2];
    __shared__ float er_s[EB2];

    const int tid = threadIdx.x;
    const int w  = tid >> 6;
    const int l  = tid & 63;
    const int lr = l & 15;
    const int lg = l >> 4;

    bf16x8 wf[8][2];
    float bias[8];
#pragma unroll
    for (int dt = 0; dt < 8; ++dt) {
        const int col = lr * 8 + dt;
        bias[dt] = b_erp[col];
#pragma unroll
        for (int s = 0; s < 2; ++s) {
            bf16x8 v;
#pragma unroll
            for (int j = 0; j < 8; ++j) {
                const int k = s * 32 + lg * 8 + j;
                v[j] = (k < NRBF) ? (short)f2bf(W_erp[k * D + col]) : (short)0;
            }
            wf[dt][s] = v;
        }
    }

    const float start = expf(-RCUT);
    const float step  = (1.0f - start) / (NRBF - 1);
    const float bq    = (2.0f / NRBF) * (1.0f - start);
    const float beta  = 1.0f / (bq * bq);

    const int prow  = tid & 63;
    const int kbase = (tid >> 6) * 16;

    // contiguous chunk range per block -> i-locality stays on one CU/XCD
    const int nchunk = NE / EB2;                       // 25000
    const int cpb = (nchunk + gridDim.x - 1) / gridDim.x;
    const int cbeg = blockIdx.x * cpb;
    const int cend = min(cbeg + cpb, nchunk);

    for (int chunk = cbeg; chunk < cend; ++chunk) {
        const int sb = chunk * EB2;
        if (tid < EB2) {
            const uint4 sv = slots[sb + tid];
            ij_s[tid][1] = (int)sv.x;                  // j
            er_s[tid]    = __expf(-__uint_as_float(sv.y));
            e_s[tid]     = (int)sv.z;                  // e
            ij_s[tid][0] = (int)sv.w;                  // i (sorted)
        }
        __syncthreads();
        {
            const float er = er_s[prow];
            const int kc0 = kbase >> 3;
#pragma unroll
            for (int c2 = 0; c2 < 2; ++c2) {
                const int kc = kc0 + c2;
                unsigned int pk[4];
#pragma unroll
                for (int p2 = 0; p2 < 4; ++p2) {
                    unsigned int word = 0;
#pragma unroll
                    for (int c = 0; c < 2; ++c) {
                        const int k = kc * 8 + p2 * 2 + c;
                        float v = 0.0f;
                        if (k < NRBF) {
                            const float diff = er - (start + (float)k * step);
                            v = __expf(-beta * diff * diff);
                        }
                        word |= ((unsigned int)f2bf(v)) << (16 * c);
                    }
                    pk[p2] = word;
                }
                const int swc = kc ^ (prow & 7);
                *(uint4*)&P[prow][swc * 8] = make_uint4(pk[0], pk[1], pk[2], pk[3]);
            }
        }
        __syncthreads();

        const int arow = w * 16 + lr;
        bf16x8 af[2];
#pragma unroll
        for (int s = 0; s < 2; ++s) {
            const int swc = (s * 4 + lg) ^ (arow & 7);
            af[s] = *(const bf16x8*)&P[arow][swc * 8];
        }

        // stage hv rows: h_bf[i] cached (sorted), h_bf[j] random
#pragma unroll
        for (int idx = tid; idx < EB2 * 16; idx += 256) {
            const int el = idx >> 4;
            const int ch = idx & 15;
            const uint4 ui = *((const uint4*)(h_bf + (size_t)ij_s[el][0] * D) + ch);
            const uint4 uj = *((const uint4*)(h_bf + (size_t)ij_s[el][1] * D) + ch);
            const unsigned int wi[4] = {ui.x, ui.y, ui.z, ui.w};
            const unsigned int wj[4] = {uj.x, uj.y, uj.z, uj.w};
            unsigned int wo[4];
#pragma unroll
            for (int p = 0; p < 4; ++p) {
                const float lo = bf2f((unsigned short)(wi[p] & 0xffff))
                               + bf2f((unsigned short)(wj[p] & 0xffff));
                const float hi = bf2f((unsigned short)(wi[p] >> 16))
                               + bf2f((unsigned short)(wj[p] >> 16));
                wo[p] = (unsigned int)f2bf(lo) | ((unsigned int)f2bf(hi) << 16);
            }
            *(uint4*)&hv[el][ch * 8] = make_uint4(wo[0], wo[1], wo[2], wo[3]);
        }
        __syncthreads();

        f32x4 accs[8];
#pragma unroll
        for (int dt = 0; dt < 8; ++dt) {
            f32x4 acc = {0.0f, 0.0f, 0.0f, 0.0f};
            acc = __builtin_amdgcn_mfma_f32_16x16x32_bf16(af[0], wf[dt][0], acc, 0, 0, 0);
            acc = __builtin_amdgcn_mfma_f32_16x16x32_bf16(af[1], wf[dt][1], acc, 0, 0, 0);
            accs[dt] = acc;
        }
#pragma unroll
        for (int q = 0; q < 4; ++q) {
            const int el = w * 16 + lg * 4 + q;
            const bf16x8 hv8 = *(const bf16x8*)&hv[el][lr * 8];
            float o[8];
#pragma unroll
            for (int dt = 0; dt < 8; ++dt)
                o[dt] = bf2f((unsigned short)hv8[dt]) * (accs[dt][q] + bias[dt]);
            float4 o0 = {o[0], o[1], o[2], o[3]};
            float4 o1 = {o[4], o[5], o[6], o[7]};
            float* tp = &t[(size_t)e_s[el] * D + lr * 8];
            *(float4*)tp       = o0;
            *(float4*)(tp + 4) = o1;
        }
        __syncthreads();
    }
}

// ---------------------------------------------------------------- aux outputs (runs LAST)
__global__ __launch_bounds__(256) void aux_kernel(
    const float* __restrict__ r, const float* __restrict__ u,
    float* __restrict__ rt0, float* __restrict__ rt1,
    float* __restrict__ rt2, float* __restrict__ cout)
{
    const int e = blockIdx.x * 256 + threadIdx.x;
    if (e >= NE) return;
    const float rr = r[e];
    rt0[e] = rr;
    const float cc = (rr < RCUT)
        ? 0.5f * (__cosf(3.14159265358979f * rr * (1.0f / RCUT)) + 1.0f)
        : 0.0f;
    cout[e] = cc;
    const float x  = u[e * 3 + 0];
    const float y  = u[e * 3 + 1];
    const float zc = u[e * 3 + 2];
    rt1[(size_t)e * 3 + 0] = x;
    rt1[(size_t)e * 3 + 1] = y;
    rt1[(size_t)e * 3 + 2] = zc;
    const float s3 = 1.7320508075688772f;
    rt2[(size_t)e * 5 + 0] = s3 * x * y;
    rt2[(size_t)e * 5 + 1] = s3 * y * zc;
    rt2[(size_t)e * 5 + 2] = 0.5f * (3.0f * zc * zc - 1.0f);
    rt2[(size_t)e * 5 + 3] = s3 * zc * x;
    rt2[(size_t)e * 5 + 4] = 0.5f * s3 * (x * x - y * y);
}

// ---------------------------------------------------------------- launch
extern "C" void kernel_launch(void* const* d_in, const int* in_sizes, int n_in,
                              void* d_out, int out_size, void* d_ws, size_t ws_size,
                              hipStream_t stream) {
    const float* z      = (const float*)d_in[0];
    const int*   edge   = (const int*)d_in[1];
    const float* r      = (const float*)d_in[2];
    const float* u      = (const float*)d_in[3];
    const float* A_na_w  = (const float*)d_in[4];
    const float* A_na_b  = (const float*)d_in[5];
    const float* A_nbr_w = (const float*)d_in[6];
    const float* A_nbr_b = (const float*)d_in[7];
    const float* W_ndp_w = (const float*)d_in[8];
    const float* W_ndp_b = (const float*)d_in[9];
    const float* W_nrd_w = (const float*)d_in[10];
    const float* W_nrd_b = (const float*)d_in[11];
    const float* W_nru_w = (const float*)d_in[12];
    const float* W_nru_b = (const float*)d_in[13];
    const float* W_erp_w = (const float*)d_in[14];
    const float* W_erp_b = (const float*)d_in[15];
    const float* ln_g    = (const float*)d_in[16];
    const float* ln_b    = (const float*)d_in[17];

    float* out = (float*)d_out;
    float* h_out   = out;
    float* t_out   = out + (size_t)NN * D;
    float* rt0_out = t_out + (size_t)NE * D;
    float* rt1_out = rt0_out + (size_t)NE;
    float* rt2_out = rt1_out + (size_t)NE * 3;
    float* c_out   = rt2_out + (size_t)NE * 5;

    // ws: nbr_bf (12.8MB) | m f32 (25.6MB) | h_bf (12.8MB)
    unsigned short* nbr_bf = (unsigned short*)d_ws;
    float* m_ws   = (float*)((char*)d_ws + (size_t)NN * D * sizeof(unsigned short));
    unsigned short* h_bf = (unsigned short*)((char*)m_ws + (size_t)NN * D * sizeof(float));

    // CSR scratch lives in the rt2 region (32MB): slots 25.6MB + off/cursor/bsum.
    // rt2/rt0/rt1/c are written LAST by aux, after edge_out consumed slots.
    uint4* slots = (uint4*)rt2_out;              // NE uint4 (25.6 MB)
    int* off     = (int*)(slots + NE);           // NN+1
    int* cursor  = off + (NN + 1);               // NN
    int* bsum    = cursor + NN;                  // 256

    hipMemsetAsync(cursor, 0, (size_t)NN * sizeof(int), stream);

    nbr_kernel<<<NN, 128, 0, stream>>>(z, A_nbr_w, A_nbr_b, nbr_bf);

    count_kernel<<<(NE + 255) / 256, 256, 0, stream>>>(edge, cursor);

    scan1_kernel<<<SCAN_B, 256, 0, stream>>>(cursor, off, bsum);
    scan2_kernel<<<1, 256, 0, stream>>>(bsum);
    scan3_kernel<<<SCAN_B, 256, 0, stream>>>(off, bsum);

    hipMemsetAsync(cursor, 0, (size_t)NN * sizeof(int), stream);

    scatter_kernel<<<(NE + 255) / 256, 256, 0, stream>>>(edge, r, off, cursor, slots);

    gather_msg_mfma<<<NN / NPB, 128, 0, stream>>>(
        slots, off, W_ndp_w, W_ndp_b, nbr_bf, m_ws);

    node_kernel2<<<NN / NB, 256, 0, stream>>>(
        z, A_na_w, A_na_b, m_ws, W_nrd_w, W_nrd_b,
        W_nru_w, W_nru_b, ln_g, ln_b, h_out, h_bf);

    edge_out_mfma<<<EDGE_GRID, 256, 0, stream>>>(
        slots, W_erp_w, W_erp_b, h_bf, t_out);

    aux_kernel<<<(NE + 255) / 256, 256, 0, stream>>>(
        r, u, rt0_out, rt1_out, rt2_out, c_out);
}

// Round 8
// 832.198 us; speedup vs baseline: 1.0287x; 1.0287x over previous
//
#include <hip/hip_runtime.h>
#include <hip/hip_bf16.h>
#include <math.h>

#define NN 50000
#define NE 1600000
#define D 128
#define NRBF 50
#define RCUT 5.0f
#define LNEPS 1e-5f
#define SCAN_B 196   // ceil(50000/256)
#define NB 16
#define NPW 8        // nodes per wave in gather
#define EO_GRID 2048

typedef __attribute__((ext_vector_type(8))) short bf16x8;
typedef __attribute__((ext_vector_type(4))) float f32x4;

__device__ __forceinline__ float silu_f(float x) {
    return x / (1.0f + __expf(-x));
}
__device__ __forceinline__ unsigned short f2bf(float x) {
    __hip_bfloat16 b = __float2bfloat16(x);
    return *reinterpret_cast<unsigned short*>(&b);
}
__device__ __forceinline__ float bf2f(unsigned short u) {
    unsigned int x = ((unsigned int)u) << 16;
    return __uint_as_float(x);
}

// ---------------------------------------------------------------- nbr
__global__ __launch_bounds__(128) void nbr_kernel(
    const float* __restrict__ z, const float* __restrict__ Aw,
    const float* __restrict__ Ab, unsigned short* __restrict__ nbr_bf)
{
    const int n = blockIdx.x;
    const int d = threadIdx.x;
    float acc = Ab[d];
#pragma unroll
    for (int k = 0; k < 25; ++k)
        acc = fmaf(z[n * 25 + k], Aw[k * D + d], acc);
    nbr_bf[(size_t)n * D + d] = f2bf(silu_f(acc));
}

// ---------------------------------------------------------------- aux + count
__global__ __launch_bounds__(256) void aux_kernel(
    const int* __restrict__ edge, const float* __restrict__ r,
    const float* __restrict__ u, float* __restrict__ rt0,
    float* __restrict__ rt1, float* __restrict__ rt2,
    float* __restrict__ cout, int* __restrict__ cnt)
{
    const int e = blockIdx.x * 256 + threadIdx.x;
    if (e >= NE) return;
    const float rr = r[e];
    __builtin_nontemporal_store(rr, &rt0[e]);
    const float cc = (rr < RCUT)
        ? 0.5f * (__cosf(3.14159265358979f * rr * (1.0f / RCUT)) + 1.0f)
        : 0.0f;
    __builtin_nontemporal_store(cc, &cout[e]);
    const float x  = u[e * 3 + 0];
    const float y  = u[e * 3 + 1];
    const float zc = u[e * 3 + 2];
    __builtin_nontemporal_store(x,  &rt1[(size_t)e * 3 + 0]);
    __builtin_nontemporal_store(y,  &rt1[(size_t)e * 3 + 1]);
    __builtin_nontemporal_store(zc, &rt1[(size_t)e * 3 + 2]);
    const float s3 = 1.7320508075688772f;
    __builtin_nontemporal_store(s3 * x * y,                  &rt2[(size_t)e * 5 + 0]);
    __builtin_nontemporal_store(s3 * y * zc,                 &rt2[(size_t)e * 5 + 1]);
    __builtin_nontemporal_store(0.5f * (3.0f * zc * zc - 1.0f), &rt2[(size_t)e * 5 + 2]);
    __builtin_nontemporal_store(s3 * zc * x,                 &rt2[(size_t)e * 5 + 3]);
    __builtin_nontemporal_store(0.5f * s3 * (x * x - y * y), &rt2[(size_t)e * 5 + 4]);
    atomicAdd(&cnt[edge[2 * e]], 1);
}

// ---------------------------------------------------------------- scans
__global__ __launch_bounds__(256) void scan1_kernel(
    const int* __restrict__ cnt, int* __restrict__ off, int* __restrict__ bsum)
{
    __shared__ int s[2][256];
    const int t = threadIdx.x;
    const int g = blockIdx.x * 256 + t;
    const int v = (g < NN) ? cnt[g] : 0;
    int incl = v;
    s[0][t] = incl;
    __syncthreads();
    int cur = 0;
#pragma unroll
    for (int dd = 1; dd < 256; dd <<= 1) {
        const int add = (t >= dd) ? s[cur][t - dd] : 0;
        incl += add;
        s[cur ^ 1][t] = incl;
        __syncthreads();
        cur ^= 1;
    }
    if (g < NN) off[g] = incl - v;
    if (t == 255) bsum[blockIdx.x] = incl;
}

__global__ __launch_bounds__(256) void scan2_kernel(int* __restrict__ bsum)
{
    __shared__ int s[2][256];
    const int t = threadIdx.x;
    const int v = (t < SCAN_B) ? bsum[t] : 0;
    int incl = v;
    s[0][t] = incl;
    __syncthreads();
    int cur = 0;
#pragma unroll
    for (int dd = 1; dd < 256; dd <<= 1) {
        const int add = (t >= dd) ? s[cur][t - dd] : 0;
        incl += add;
        s[cur ^ 1][t] = incl;
        __syncthreads();
        cur ^= 1;
    }
    if (t < SCAN_B) bsum[t] = incl - v;
}

__global__ __launch_bounds__(256) void scan3_kernel(
    int* __restrict__ off, const int* __restrict__ bsum)
{
    const int g = blockIdx.x * 256 + threadIdx.x;
    if (g < NN) off[g] += bsum[blockIdx.x];
    if (g == 0) off[NN] = NE;
}

// ---------------------------------------------------------------- scatter {j, r}
__global__ __launch_bounds__(256) void scatter_kernel(
    const int* __restrict__ edge, const float* __restrict__ r,
    const int* __restrict__ off, int* __restrict__ cursor,
    uint2* __restrict__ jr)
{
    const int e = blockIdx.x * 256 + threadIdx.x;
    if (e >= NE) return;
    const int2 ep = ((const int2*)edge)[e];
    const int pos = atomicAdd(&cursor[ep.x], 1);
    uint2 v;
    v.x = (unsigned int)ep.y;
    v.y = __float_as_uint(r[e]);
    jr[off[ep.x] + pos] = v;
}

// ---------------------------------------------------------------- gather msg
// Wave-autonomous, LDS-free. Wave owns NPW nodes; per 16-edge batch the
// A-fragment (c-scaled rbf, bias row at k=50) is computed IN REGISTERS:
// af[s][j] = P[lr][s*32+lg*8+j], needing only (er,c) of edge lr via shfl.
// col map: col = lr*8 + dt (dt 0..7).
__global__ __launch_bounds__(256) void gather_msg_wave(
    const uint2* __restrict__ jr, const int* __restrict__ off,
    const float* __restrict__ W_ndp, const float* __restrict__ b_ndp,
    const unsigned short* __restrict__ nbr_bf, float* __restrict__ m)
{
    const int tid = threadIdx.x;
    const int w   = tid >> 6;
    const int l   = tid & 63;
    const int lr  = l & 15;
    const int lg  = l >> 4;

    bf16x8 wf[8][2];
#pragma unroll
    for (int dt = 0; dt < 8; ++dt) {
        const int col = lr * 8 + dt;
#pragma unroll
        for (int s = 0; s < 2; ++s) {
            bf16x8 v;
#pragma unroll
            for (int j = 0; j < 8; ++j) {
                const int k = s * 32 + lg * 8 + j;
                float wv = 0.0f;
                if (k < NRBF)       wv = W_ndp[k * D + col];
                else if (k == NRBF) wv = b_ndp[col];
                v[j] = (short)f2bf(wv);
            }
            wf[dt][s] = v;
        }
    }

    const float start = expf(-RCUT);
    const float step  = (1.0f - start) / (NRBF - 1);
    const float bq    = (2.0f / NRBF) * (1.0f - start);
    const float beta  = 1.0f / (bq * bq);

    const int wid = blockIdx.x * 4 + w;

    for (int nn = 0; nn < NPW; ++nn) {
        const int n = wid * NPW + nn;
        if (n >= NN) break;
        const int s0  = off[n];
        const int deg = off[n + 1] - s0;

        f32x4 macc[8] = {{0,0,0,0},{0,0,0,0},{0,0,0,0},{0,0,0,0},
                         {0,0,0,0},{0,0,0,0},{0,0,0,0},{0,0,0,0}};

        for (int base = 0; base < deg; base += 16) {
            // lanes 0..15 load {j,r}
            unsigned int jv = 0;
            float er = 0.0f, cc = 0.0f;
            if (l < 16 && l < deg - base) {
                const uint2 v = jr[s0 + base + l];
                jv = v.x;
                const float rr = __uint_as_float(v.y);
                er = __expf(-rr);
                cc = (rr < RCUT)
                    ? 0.5f * (__cosf(3.14159265358979f * rr * (1.0f / RCUT)) + 1.0f)
                    : 0.0f;
            }
            const float erL = __shfl(er, lr);
            const float ccL = __shfl(cc, lr);

            // A-fragments in registers
            bf16x8 af[2];
#pragma unroll
            for (int s = 0; s < 2; ++s) {
                bf16x8 a;
#pragma unroll
                for (int j = 0; j < 8; ++j) {
                    const int k = s * 32 + lg * 8 + j;
                    float pv = 0.0f;
                    if (k < NRBF) {
                        const float diff = erL - (start + (float)k * step);
                        pv = ccL * __expf(-beta * diff * diff);
                    } else if (k == NRBF) {
                        pv = ccL;
                    }
                    a[j] = (short)f2bf(pv);
                }
                af[s] = a;
            }

            f32x4 accs[8];
#pragma unroll
            for (int dt = 0; dt < 8; ++dt) {
                f32x4 acc = {0.0f, 0.0f, 0.0f, 0.0f};
                acc = __builtin_amdgcn_mfma_f32_16x16x32_bf16(af[0], wf[dt][0], acc, 0, 0, 0);
                acc = __builtin_amdgcn_mfma_f32_16x16x32_bf16(af[1], wf[dt][1], acc, 0, 0, 0);
                accs[dt] = acc;
            }
#pragma unroll
            for (int q = 0; q < 4; ++q) {
                const int jrow = __shfl((int)jv, lg * 4 + q);
                const bf16x8 nv8 = *(const bf16x8*)(nbr_bf + (size_t)jrow * D + lr * 8);
#pragma unroll
                for (int dt = 0; dt < 8; ++dt)
                    macc[dt][q] = fmaf(bf2f((unsigned short)nv8[dt]), accs[dt][q], macc[dt][q]);
            }
        }

        float vv[8];
#pragma unroll
        for (int dt = 0; dt < 8; ++dt) {
            float v = macc[dt][0] + macc[dt][1] + macc[dt][2] + macc[dt][3];
            v += __shfl_xor(v, 16);
            v += __shfl_xor(v, 32);
            vv[dt] = v;
        }
        if (lg == 0) {
            f32x4 o0 = {vv[0], vv[1], vv[2], vv[3]};
            f32x4 o1 = {vv[4], vv[5], vv[6], vv[7]};
            float* mp = &m[(size_t)n * D + lr * 8];
            *(f32x4*)mp       = o0;
            *(f32x4*)(mp + 4) = o1;
        }
    }
}

// ---------------------------------------------------------------- node MLP
__global__ __launch_bounds__(256) void node_kernel2(
    const float* __restrict__ z, const float* __restrict__ A_na_w,
    const float* __restrict__ A_na_b, const float* __restrict__ m,
    const float* __restrict__ W_nrd_w, const float* __restrict__ W_nrd_b,
    const float* __restrict__ W_nru_w, const float* __restrict__ W_nru_b,
    const float* __restrict__ ln_g, const float* __restrict__ ln_b,
    float* __restrict__ hout, unsigned short* __restrict__ h_bf)
{
    __shared__ float inbuf[NB][260];
    __shared__ float wbuf[32][128];
    __shared__ float part[4][NB][2];

    const int tid = threadIdx.x;
    const int n0 = blockIdx.x * NB;
    const int nl = tid & 15;
    const int dg = tid >> 4;

    for (int idx = tid; idx < NB * 128; idx += 256) {
        const int n = idx >> 7;
        const int d = idx & 127;
        float acc = A_na_b[d];
#pragma unroll
        for (int k = 0; k < 25; ++k)
            acc = fmaf(z[(size_t)(n0 + n) * 25 + k], A_na_w[k * D + d], acc);
        inbuf[n][d]       = silu_f(acc);
        inbuf[n][128 + d] = m[(size_t)(n0 + n) * D + d];
    }

    float h1[8];
#pragma unroll
    for (int dd = 0; dd < 8; ++dd) h1[dd] = W_nrd_b[dg * 8 + dd];

    for (int tile = 0; tile < 8; ++tile) {
        __syncthreads();
        for (int v = tid; v < 32 * 32; v += 256) {
            const int row = v >> 5;
            const int c4  = (v & 31) * 4;
            *(float4*)&wbuf[row][c4] =
                *(const float4*)&W_nrd_w[(size_t)(tile * 32 + row) * D + c4];
        }
        __syncthreads();
#pragma unroll 4
        for (int k = 0; k < 32; ++k) {
            const float rin = inbuf[nl][tile * 32 + k];
            const float4 wa = *(const float4*)&wbuf[k][dg * 8];
            const float4 wb = *(const float4*)&wbuf[k][dg * 8 + 4];
            h1[0] = fmaf(rin, wa.x, h1[0]);
            h1[1] = fmaf(rin, wa.y, h1[1]);
            h1[2] = fmaf(rin, wa.z, h1[2]);
            h1[3] = fmaf(rin, wa.w, h1[3]);
            h1[4] = fmaf(rin, wb.x, h1[4]);
            h1[5] = fmaf(rin, wb.y, h1[5]);
            h1[6] = fmaf(rin, wb.z, h1[6]);
            h1[7] = fmaf(rin, wb.w, h1[7]);
        }
    }

    float s = 0.0f, sq = 0.0f;
#pragma unroll
    for (int dd = 0; dd < 8; ++dd) { s += h1[dd]; sq += h1[dd] * h1[dd]; }
    s  += __shfl_xor(s, 16);  sq += __shfl_xor(sq, 16);
    s  += __shfl_xor(s, 32);  sq += __shfl_xor(sq, 32);
    const int wv = tid >> 6;
    if ((tid & 63) < 16) { part[wv][nl][0] = s; part[wv][nl][1] = sq; }
    __syncthreads();
    float ts = 0.0f, tsq = 0.0f;
#pragma unroll
    for (int w = 0; w < 4; ++w) { ts += part[w][nl][0]; tsq += part[w][nl][1]; }
    const float mu  = ts * (1.0f / 128.0f);
    const float var = tsq * (1.0f / 128.0f) - mu * mu;
    const float inv = rsqrtf(var + LNEPS);

#pragma unroll
    for (int dd = 0; dd < 8; ++dd) {
        const int d = dg * 8 + dd;
        inbuf[nl][d] = silu_f((h1[dd] - mu) * inv * ln_g[d] + ln_b[d]);
    }

    float h2[8];
#pragma unroll
    for (int dd = 0; dd < 8; ++dd) h2[dd] = W_nru_b[dg * 8 + dd];

    for (int tile = 0; tile < 4; ++tile) {
        __syncthreads();
        for (int v = tid; v < 32 * 32; v += 256) {
            const int row = v >> 5;
            const int c4  = (v & 31) * 4;
            *(float4*)&wbuf[row][c4] =
                *(const float4*)&W_nru_w[(size_t)(tile * 32 + row) * D + c4];
        }
        __syncthreads();
#pragma unroll 4
        for (int k = 0; k < 32; ++k) {
            const float rin = inbuf[nl][tile * 32 + k];
            const float4 wa = *(const float4*)&wbuf[k][dg * 8];
            const float4 wb = *(const float4*)&wbuf[k][dg * 8 + 4];
            h2[0] = fmaf(rin, wa.x, h2[0]);
            h2[1] = fmaf(rin, wa.y, h2[1]);
            h2[2] = fmaf(rin, wa.z, h2[2]);
            h2[3] = fmaf(rin, wa.w, h2[3]);
            h2[4] = fmaf(rin, wb.x, h2[4]);
            h2[5] = fmaf(rin, wb.y, h2[5]);
            h2[6] = fmaf(rin, wb.z, h2[6]);
            h2[7] = fmaf(rin, wb.w, h2[7]);
        }
    }

    f32x4 o0 = {h2[0], h2[1], h2[2], h2[3]};
    f32x4 o1 = {h2[4], h2[5], h2[6], h2[7]};
    float* hp = &hout[(size_t)(n0 + nl) * D + dg * 8];
    __builtin_nontemporal_store(o0, (f32x4*)hp);
    __builtin_nontemporal_store(o1, (f32x4*)(hp + 4));

    unsigned int b0 = (unsigned int)f2bf(h2[0]) | ((unsigned int)f2bf(h2[1]) << 16);
    unsigned int b1 = (unsigned int)f2bf(h2[2]) | ((unsigned int)f2bf(h2[3]) << 16);
    unsigned int b2 = (unsigned int)f2bf(h2[4]) | ((unsigned int)f2bf(h2[5]) << 16);
    unsigned int b3 = (unsigned int)f2bf(h2[6]) | ((unsigned int)f2bf(h2[7]) << 16);
    *(uint4*)&h_bf[(size_t)(n0 + nl) * D + dg * 8] = make_uint4(b0, b1, b2, b3);
}

// ---------------------------------------------------------------- edge out
// Wave-autonomous, LDS-free, e-order. Wave owns a 16-edge group: A-fragment
// (rbf) computed in registers; epilogue gathers h_bf[i], h_bf[j] as bf16x8
// (16 lanes cover a full 256B row); nontemporal t stores.
// col map: col = lr*8 + dt.
__global__ __launch_bounds__(256) void edge_out_wave(
    const int* __restrict__ edge, const float* __restrict__ r,
    const float* __restrict__ W_erp, const float* __restrict__ b_erp,
    const unsigned short* __restrict__ h_bf, float* __restrict__ t)
{
    const int tid = threadIdx.x;
    const int w   = tid >> 6;
    const int l   = tid & 63;
    const int lr  = l & 15;
    const int lg  = l >> 4;

    bf16x8 wf[8][2];
    float bias[8];
#pragma unroll
    for (int dt = 0; dt < 8; ++dt) {
        const int col = lr * 8 + dt;
        bias[dt] = b_erp[col];
#pragma unroll
        for (int s = 0; s < 2; ++s) {
            bf16x8 v;
#pragma unroll
            for (int j = 0; j < 8; ++j) {
                const int k = s * 32 + lg * 8 + j;
                v[j] = (k < NRBF) ? (short)f2bf(W_erp[k * D + col]) : (short)0;
            }
            wf[dt][s] = v;
        }
    }

    const float start = expf(-RCUT);
    const float step  = (1.0f - start) / (NRBF - 1);
    const float bq    = (2.0f / NRBF) * (1.0f - start);
    const float beta  = 1.0f / (bq * bq);

    const int wid = blockIdx.x * 4 + w;
    const int nw  = gridDim.x * 4;
    const int ngroup = NE / 16;

    for (int g = wid; g < ngroup; g += nw) {
        const int eb = g * 16;
        int iv = 0, jv = 0;
        float er = 0.0f;
        if (l < 16) {
            const int2 ep = ((const int2*)edge)[eb + l];
            iv = ep.x;
            jv = ep.y;
            er = __expf(-r[eb + l]);
        }
        const float erL = __shfl(er, lr);

        bf16x8 af[2];
#pragma unroll
        for (int s = 0; s < 2; ++s) {
            bf16x8 a;
#pragma unroll
            for (int j = 0; j < 8; ++j) {
                const int k = s * 32 + lg * 8 + j;
                float pv = 0.0f;
                if (k < NRBF) {
                    const float diff = erL - (start + (float)k * step);
                    pv = __expf(-beta * diff * diff);
                }
                a[j] = (short)f2bf(pv);
            }
            af[s] = a;
        }

        f32x4 accs[8];
#pragma unroll
        for (int dt = 0; dt < 8; ++dt) {
            f32x4 acc = {0.0f, 0.0f, 0.0f, 0.0f};
            acc = __builtin_amdgcn_mfma_f32_16x16x32_bf16(af[0], wf[dt][0], acc, 0, 0, 0);
            acc = __builtin_amdgcn_mfma_f32_16x16x32_bf16(af[1], wf[dt][1], acc, 0, 0, 0);
            accs[dt] = acc;
        }

#pragma unroll
        for (int q = 0; q < 4; ++q) {
            const int irow = __shfl(iv, lg * 4 + q);
            const int jrow = __shfl(jv, lg * 4 + q);
            const bf16x8 hi8 = *(const bf16x8*)(h_bf + (size_t)irow * D + lr * 8);
            const bf16x8 hj8 = *(const bf16x8*)(h_bf + (size_t)jrow * D + lr * 8);
            float o[8];
#pragma unroll
            for (int dt = 0; dt < 8; ++dt) {
                const float hvf = bf2f((unsigned short)hi8[dt]) + bf2f((unsigned short)hj8[dt]);
                o[dt] = hvf * (accs[dt][q] + bias[dt]);
            }
            f32x4 o0 = {o[0], o[1], o[2], o[3]};
            f32x4 o1 = {o[4], o[5], o[6], o[7]};
            float* tp = &t[(size_t)(eb + lg * 4 + q) * D + lr * 8];
            __builtin_nontemporal_store(o0, (f32x4*)tp);
            __builtin_nontemporal_store(o1, (f32x4*)(tp + 4));
        }
    }
}

// ---------------------------------------------------------------- launch
extern "C" void kernel_launch(void* const* d_in, const int* in_sizes, int n_in,
                              void* d_out, int out_size, void* d_ws, size_t ws_size,
                              hipStream_t stream) {
    const float* z      = (const float*)d_in[0];
    const int*   edge   = (const int*)d_in[1];
    const float* r      = (const float*)d_in[2];
    const float* u      = (const float*)d_in[3];
    const float* A_na_w  = (const float*)d_in[4];
    const float* A_na_b  = (const float*)d_in[5];
    const float* A_nbr_w = (const float*)d_in[6];
    const float* A_nbr_b = (const float*)d_in[7];
    const float* W_ndp_w = (const float*)d_in[8];
    const float* W_ndp_b = (const float*)d_in[9];
    const float* W_nrd_w = (const float*)d_in[10];
    const float* W_nrd_b = (const float*)d_in[11];
    const float* W_nru_w = (const float*)d_in[12];
    const float* W_nru_b = (const float*)d_in[13];
    const float* W_erp_w = (const float*)d_in[14];
    const float* W_erp_b = (const float*)d_in[15];
    const float* ln_g    = (const float*)d_in[16];
    const float* ln_b    = (const float*)d_in[17];

    float* out = (float*)d_out;
    float* h_out   = out;
    float* t_out   = out + (size_t)NN * D;
    float* rt0_out = t_out + (size_t)NE * D;
    float* rt1_out = rt0_out + (size_t)NE;
    float* rt2_out = rt1_out + (size_t)NE * 3;
    float* c_out   = rt2_out + (size_t)NE * 5;

    // ws: nbr_bf (12.8MB) | m f32 (25.6MB) | h_bf (12.8MB)
    unsigned short* nbr_bf = (unsigned short*)d_ws;
    float* m_ws   = (float*)((char*)d_ws + (size_t)NN * D * sizeof(unsigned short));
    unsigned short* h_bf = (unsigned short*)((char*)m_ws + (size_t)NN * D * sizeof(float));

    // CSR scratch in the t region (819MB): consumed by gather_msg, which
    // finishes before edge_out overwrites t (stream order).
    uint2* jr   = (uint2*)t_out;                 // NE uint2 (12.8 MB)
    int* off    = (int*)(jr + NE);               // NN+1
    int* cursor = off + (NN + 1);                // NN
    int* bsum   = cursor + NN;                   // 256

    hipMemsetAsync(cursor, 0, (size_t)NN * sizeof(int), stream);

    nbr_kernel<<<NN, 128, 0, stream>>>(z, A_nbr_w, A_nbr_b, nbr_bf);

    aux_kernel<<<(NE + 255) / 256, 256, 0, stream>>>(
        edge, r, u, rt0_out, rt1_out, rt2_out, c_out, cursor);

    scan1_kernel<<<SCAN_B, 256, 0, stream>>>(cursor, off, bsum);
    scan2_kernel<<<1, 256, 0, stream>>>(bsum);
    scan3_kernel<<<SCAN_B, 256, 0, stream>>>(off, bsum);

    hipMemsetAsync(cursor, 0, (size_t)NN * sizeof(int), stream);

    scatter_kernel<<<(NE + 255) / 256, 256, 0, stream>>>(edge, r, off, cursor, jr);

    {
        const int nwaves = (NN + NPW - 1) / NPW;          // 6250
        const int blocks = (nwaves + 3) / 4;              // 1563
        gather_msg_wave<<<blocks, 256, 0, stream>>>(
            jr, off, W_ndp_w, W_ndp_b, nbr_bf, m_ws);
    }

    node_kernel2<<<NN / NB, 256, 0, stream>>>(
        z, A_na_w, A_na_b, m_ws, W_nrd_w, W_nrd_b,
        W_nru_w, W_nru_b, ln_g, ln_b, h_out, h_bf);

    edge_out_wave<<<EO_GRID, 256, 0, stream>>>(
        edge, r, W_erp_w, W_erp_b, h_bf, t_out);
}

// Round 9
// 829.623 us; speedup vs baseline: 1.0319x; 1.0031x over previous
//
#include <hip/hip_runtime.h>
#include <hip/hip_bf16.h>
#include <math.h>

#define NN 50000
#define NE 1600000
#define D 128
#define NRBF 50
#define RCUT 5.0f
#define LNEPS 1e-5f
#define SCAN_B 196   // ceil(50000/256)
#define NB 16
#define NPW 8        // nodes per wave in gather
#define EO_GRID 2048

typedef __attribute__((ext_vector_type(8))) short bf16x8;
typedef __attribute__((ext_vector_type(4))) float f32x4;

__device__ __forceinline__ float silu_f(float x) {
    return x / (1.0f + __expf(-x));
}
__device__ __forceinline__ unsigned short f2bf(float x) {
    __hip_bfloat16 b = __float2bfloat16(x);
    return *reinterpret_cast<unsigned short*>(&b);
}
__device__ __forceinline__ float bf2f(unsigned short u) {
    unsigned int x = ((unsigned int)u) << 16;
    return __uint_as_float(x);
}

// ---------------------------------------------------------------- nbr
__global__ __launch_bounds__(128) void nbr_kernel(
    const float* __restrict__ z, const float* __restrict__ Aw,
    const float* __restrict__ Ab, unsigned short* __restrict__ nbr_bf)
{
    const int n = blockIdx.x;
    const int d = threadIdx.x;
    float acc = Ab[d];
#pragma unroll
    for (int k = 0; k < 25; ++k)
        acc = fmaf(z[n * 25 + k], Aw[k * D + d], acc);
    nbr_bf[(size_t)n * D + d] = f2bf(silu_f(acc));
}

// ---------------------------------------------------------------- aux + count
__global__ __launch_bounds__(256) void aux_kernel(
    const int* __restrict__ edge, const float* __restrict__ r,
    const float* __restrict__ u, float* __restrict__ rt0,
    float* __restrict__ rt1, float* __restrict__ rt2,
    float* __restrict__ cout, int* __restrict__ cnt)
{
    const int e = blockIdx.x * 256 + threadIdx.x;
    if (e >= NE) return;
    const float rr = r[e];
    __builtin_nontemporal_store(rr, &rt0[e]);
    const float cc = (rr < RCUT)
        ? 0.5f * (__cosf(3.14159265358979f * rr * (1.0f / RCUT)) + 1.0f)
        : 0.0f;
    __builtin_nontemporal_store(cc, &cout[e]);
    const float x  = u[e * 3 + 0];
    const float y  = u[e * 3 + 1];
    const float zc = u[e * 3 + 2];
    __builtin_nontemporal_store(x,  &rt1[(size_t)e * 3 + 0]);
    __builtin_nontemporal_store(y,  &rt1[(size_t)e * 3 + 1]);
    __builtin_nontemporal_store(zc, &rt1[(size_t)e * 3 + 2]);
    const float s3 = 1.7320508075688772f;
    __builtin_nontemporal_store(s3 * x * y,                  &rt2[(size_t)e * 5 + 0]);
    __builtin_nontemporal_store(s3 * y * zc,                 &rt2[(size_t)e * 5 + 1]);
    __builtin_nontemporal_store(0.5f * (3.0f * zc * zc - 1.0f), &rt2[(size_t)e * 5 + 2]);
    __builtin_nontemporal_store(s3 * zc * x,                 &rt2[(size_t)e * 5 + 3]);
    __builtin_nontemporal_store(0.5f * s3 * (x * x - y * y), &rt2[(size_t)e * 5 + 4]);
    atomicAdd(&cnt[edge[2 * e]], 1);
}

// ---------------------------------------------------------------- scans
__global__ __launch_bounds__(256) void scan1_kernel(
    const int* __restrict__ cnt, int* __restrict__ off, int* __restrict__ bsum)
{
    __shared__ int s[2][256];
    const int t = threadIdx.x;
    const int g = blockIdx.x * 256 + t;
    const int v = (g < NN) ? cnt[g] : 0;
    int incl = v;
    s[0][t] = incl;
    __syncthreads();
    int cur = 0;
#pragma unroll
    for (int dd = 1; dd < 256; dd <<= 1) {
        const int add = (t >= dd) ? s[cur][t - dd] : 0;
        incl += add;
        s[cur ^ 1][t] = incl;
        __syncthreads();
        cur ^= 1;
    }
    if (g < NN) off[g] = incl - v;
    if (t == 255) bsum[blockIdx.x] = incl;
}

__global__ __launch_bounds__(256) void scan2_kernel(int* __restrict__ bsum)
{
    __shared__ int s[2][256];
    const int t = threadIdx.x;
    const int v = (t < SCAN_B) ? bsum[t] : 0;
    int incl = v;
    s[0][t] = incl;
    __syncthreads();
    int cur = 0;
#pragma unroll
    for (int dd = 1; dd < 256; dd <<= 1) {
        const int add = (t >= dd) ? s[cur][t - dd] : 0;
        incl += add;
        s[cur ^ 1][t] = incl;
        __syncthreads();
        cur ^= 1;
    }
    if (t < SCAN_B) bsum[t] = incl - v;
}

__global__ __launch_bounds__(256) void scan3_kernel(
    int* __restrict__ off, const int* __restrict__ bsum)
{
    const int g = blockIdx.x * 256 + threadIdx.x;
    if (g < NN) off[g] += bsum[blockIdx.x];
    if (g == 0) off[NN] = NE;
}

// ---------------------------------------------------------------- scatter {j, r}
__global__ __launch_bounds__(256) void scatter_kernel(
    const int* __restrict__ edge, const float* __restrict__ r,
    const int* __restrict__ off, int* __restrict__ cursor,
    uint2* __restrict__ jr)
{
    const int e = blockIdx.x * 256 + threadIdx.x;
    if (e >= NE) return;
    const int2 ep = ((const int2*)edge)[e];
    const int pos = atomicAdd(&cursor[ep.x], 1);
    uint2 v;
    v.x = (unsigned int)ep.y;
    v.y = __float_as_uint(r[e]);
    jr[off[ep.x] + pos] = v;
}

// ---------------------------------------------------------------- gather msg
// Wave-autonomous, LDS-free, 2-stage software pipeline:
//   decode head -> prefetch NEXT head -> issue nbr gathers -> A-frag VALU
//   -> MFMA folded with epilogue (gather latency hidden under compute).
// col map: col = lr*8 + dt.
__global__ __launch_bounds__(256, 3) void gather_msg_wave(
    const uint2* __restrict__ jr, const int* __restrict__ off,
    const float* __restrict__ W_ndp, const float* __restrict__ b_ndp,
    const unsigned short* __restrict__ nbr_bf, float* __restrict__ m)
{
    const int tid = threadIdx.x;
    const int w   = tid >> 6;
    const int l   = tid & 63;
    const int lr  = l & 15;
    const int lg  = l >> 4;

    bf16x8 wf[8][2];
#pragma unroll
    for (int dt = 0; dt < 8; ++dt) {
        const int col = lr * 8 + dt;
#pragma unroll
        for (int s = 0; s < 2; ++s) {
            bf16x8 v;
#pragma unroll
            for (int j = 0; j < 8; ++j) {
                const int k = s * 32 + lg * 8 + j;
                float wv = 0.0f;
                if (k < NRBF)       wv = W_ndp[k * D + col];
                else if (k == NRBF) wv = b_ndp[col];
                v[j] = (short)f2bf(wv);
            }
            wf[dt][s] = v;
        }
    }

    const float start = expf(-RCUT);
    const float step  = (1.0f - start) / (NRBF - 1);
    const float bq    = (2.0f / NRBF) * (1.0f - start);
    const float beta  = 1.0f / (bq * bq);

    const int wid = blockIdx.x * 4 + w;

    for (int nn = 0; nn < NPW; ++nn) {
        const int n = wid * NPW + nn;
        if (n >= NN) break;
        const int s0  = off[n];
        const int deg = off[n + 1] - s0;

        f32x4 macc[8] = {{0,0,0,0},{0,0,0,0},{0,0,0,0},{0,0,0,0},
                         {0,0,0,0},{0,0,0,0},{0,0,0,0},{0,0,0,0}};

        // prologue: head for batch 0
        uint2 v = make_uint2(0u, 0u);
        if (l < 16 && l < deg) v = jr[s0 + l];

        for (int base = 0; base < deg; base += 16) {
            // decode current head (explicit validity mask)
            const bool val = (l < 16) && (base + l < deg);
            const unsigned int jv = val ? v.x : 0u;
            float er = 0.0f, cc = 0.0f;
            if (val) {
                const float rr = __uint_as_float(v.y);
                er = __expf(-rr);
                cc = (rr < RCUT)
                    ? 0.5f * (__cosf(3.14159265358979f * rr * (1.0f / RCUT)) + 1.0f)
                    : 0.0f;
            }
            // prefetch next head (hides under this batch's compute)
            uint2 vn = make_uint2(0u, 0u);
            if (l < 16 && base + 16 + l < deg) vn = jr[s0 + base + 16 + l];

            const float erL = __shfl(er, lr);
            const float ccL = __shfl(cc, lr);

            // issue the 4 random nbr gathers BEFORE the heavy VALU block
            bf16x8 nv0, nv1, nv2, nv3;
            {
                const int j0 = __shfl((int)jv, lg * 4 + 0);
                const int j1 = __shfl((int)jv, lg * 4 + 1);
                const int j2 = __shfl((int)jv, lg * 4 + 2);
                const int j3 = __shfl((int)jv, lg * 4 + 3);
                nv0 = *(const bf16x8*)(nbr_bf + (size_t)j0 * D + lr * 8);
                nv1 = *(const bf16x8*)(nbr_bf + (size_t)j1 * D + lr * 8);
                nv2 = *(const bf16x8*)(nbr_bf + (size_t)j2 * D + lr * 8);
                nv3 = *(const bf16x8*)(nbr_bf + (size_t)j3 * D + lr * 8);
            }

            // A-fragments in registers (c-scaled rbf; bias row k=50)
            bf16x8 af[2];
#pragma unroll
            for (int s = 0; s < 2; ++s) {
                bf16x8 a;
#pragma unroll
                for (int j = 0; j < 8; ++j) {
                    const int k = s * 32 + lg * 8 + j;
                    float pv = 0.0f;
                    if (k < NRBF) {
                        const float diff = erL - (start + (float)k * step);
                        pv = ccL * __expf(-beta * diff * diff);
                    } else if (k == NRBF) {
                        pv = ccL;
                    }
                    a[j] = (short)f2bf(pv);
                }
                af[s] = a;
            }

#pragma unroll
            for (int dt = 0; dt < 8; ++dt) {
                f32x4 acc = {0.0f, 0.0f, 0.0f, 0.0f};
                acc = __builtin_amdgcn_mfma_f32_16x16x32_bf16(af[0], wf[dt][0], acc, 0, 0, 0);
                acc = __builtin_amdgcn_mfma_f32_16x16x32_bf16(af[1], wf[dt][1], acc, 0, 0, 0);
                macc[dt][0] = fmaf(bf2f((unsigned short)nv0[dt]), acc[0], macc[dt][0]);
                macc[dt][1] = fmaf(bf2f((unsigned short)nv1[dt]), acc[1], macc[dt][1]);
                macc[dt][2] = fmaf(bf2f((unsigned short)nv2[dt]), acc[2], macc[dt][2]);
                macc[dt][3] = fmaf(bf2f((unsigned short)nv3[dt]), acc[3], macc[dt][3]);
            }
            v = vn;
        }

        float vv[8];
#pragma unroll
        for (int dt = 0; dt < 8; ++dt) {
            float x = macc[dt][0] + macc[dt][1] + macc[dt][2] + macc[dt][3];
            x += __shfl_xor(x, 16);
            x += __shfl_xor(x, 32);
            vv[dt] = x;
        }
        if (lg == 0) {
            f32x4 o0 = {vv[0], vv[1], vv[2], vv[3]};
            f32x4 o1 = {vv[4], vv[5], vv[6], vv[7]};
            float* mp = &m[(size_t)n * D + lr * 8];
            *(f32x4*)mp       = o0;
            *(f32x4*)(mp + 4) = o1;
        }
    }
}

// ---------------------------------------------------------------- node MLP
__global__ __launch_bounds__(256) void node_kernel2(
    const float* __restrict__ z, const float* __restrict__ A_na_w,
    const float* __restrict__ A_na_b, const float* __restrict__ m,
    const float* __restrict__ W_nrd_w, const float* __restrict__ W_nrd_b,
    const float* __restrict__ W_nru_w, const float* __restrict__ W_nru_b,
    const float* __restrict__ ln_g, const float* __restrict__ ln_b,
    float* __restrict__ hout, unsigned short* __restrict__ h_bf)
{
    __shared__ float inbuf[NB][260];
    __shared__ float wbuf[32][128];
    __shared__ float part[4][NB][2];

    const int tid = threadIdx.x;
    const int n0 = blockIdx.x * NB;
    const int nl = tid & 15;
    const int dg = tid >> 4;

    for (int idx = tid; idx < NB * 128; idx += 256) {
        const int n = idx >> 7;
        const int d = idx & 127;
        float acc = A_na_b[d];
#pragma unroll
        for (int k = 0; k < 25; ++k)
            acc = fmaf(z[(size_t)(n0 + n) * 25 + k], A_na_w[k * D + d], acc);
        inbuf[n][d]       = silu_f(acc);
        inbuf[n][128 + d] = m[(size_t)(n0 + n) * D + d];
    }

    float h1[8];
#pragma unroll
    for (int dd = 0; dd < 8; ++dd) h1[dd] = W_nrd_b[dg * 8 + dd];

    for (int tile = 0; tile < 8; ++tile) {
        __syncthreads();
        for (int v = tid; v < 32 * 32; v += 256) {
            const int row = v >> 5;
            const int c4  = (v & 31) * 4;
            *(float4*)&wbuf[row][c4] =
                *(const float4*)&W_nrd_w[(size_t)(tile * 32 + row) * D + c4];
        }
        __syncthreads();
#pragma unroll 4
        for (int k = 0; k < 32; ++k) {
            const float rin = inbuf[nl][tile * 32 + k];
            const float4 wa = *(const float4*)&wbuf[k][dg * 8];
            const float4 wb = *(const float4*)&wbuf[k][dg * 8 + 4];
            h1[0] = fmaf(rin, wa.x, h1[0]);
            h1[1] = fmaf(rin, wa.y, h1[1]);
            h1[2] = fmaf(rin, wa.z, h1[2]);
            h1[3] = fmaf(rin, wa.w, h1[3]);
            h1[4] = fmaf(rin, wb.x, h1[4]);
            h1[5] = fmaf(rin, wb.y, h1[5]);
            h1[6] = fmaf(rin, wb.z, h1[6]);
            h1[7] = fmaf(rin, wb.w, h1[7]);
        }
    }

    float s = 0.0f, sq = 0.0f;
#pragma unroll
    for (int dd = 0; dd < 8; ++dd) { s += h1[dd]; sq += h1[dd] * h1[dd]; }
    s  += __shfl_xor(s, 16);  sq += __shfl_xor(sq, 16);
    s  += __shfl_xor(s, 32);  sq += __shfl_xor(sq, 32);
    const int wv = tid >> 6;
    if ((tid & 63) < 16) { part[wv][nl][0] = s; part[wv][nl][1] = sq; }
    __syncthreads();
    float ts = 0.0f, tsq = 0.0f;
#pragma unroll
    for (int w = 0; w < 4; ++w) { ts += part[w][nl][0]; tsq += part[w][nl][1]; }
    const float mu  = ts * (1.0f / 128.0f);
    const float var = tsq * (1.0f / 128.0f) - mu * mu;
    const float inv = rsqrtf(var + LNEPS);

#pragma unroll
    for (int dd = 0; dd < 8; ++dd) {
        const int d = dg * 8 + dd;
        inbuf[nl][d] = silu_f((h1[dd] - mu) * inv * ln_g[d] + ln_b[d]);
    }

    float h2[8];
#pragma unroll
    for (int dd = 0; dd < 8; ++dd) h2[dd] = W_nru_b[dg * 8 + dd];

    for (int tile = 0; tile < 4; ++tile) {
        __syncthreads();
        for (int v = tid; v < 32 * 32; v += 256) {
            const int row = v >> 5;
            const int c4  = (v & 31) * 4;
            *(float4*)&wbuf[row][c4] =
                *(const float4*)&W_nru_w[(size_t)(tile * 32 + row) * D + c4];
        }
        __syncthreads();
#pragma unroll 4
        for (int k = 0; k < 32; ++k) {
            const float rin = inbuf[nl][tile * 32 + k];
            const float4 wa = *(const float4*)&wbuf[k][dg * 8];
            const float4 wb = *(const float4*)&wbuf[k][dg * 8 + 4];
            h2[0] = fmaf(rin, wa.x, h2[0]);
            h2[1] = fmaf(rin, wa.y, h2[1]);
            h2[2] = fmaf(rin, wa.z, h2[2]);
            h2[3] = fmaf(rin, wa.w, h2[3]);
            h2[4] = fmaf(rin, wb.x, h2[4]);
            h2[5] = fmaf(rin, wb.y, h2[5]);
            h2[6] = fmaf(rin, wb.z, h2[6]);
            h2[7] = fmaf(rin, wb.w, h2[7]);
        }
    }

    f32x4 o0 = {h2[0], h2[1], h2[2], h2[3]};
    f32x4 o1 = {h2[4], h2[5], h2[6], h2[7]};
    float* hp = &hout[(size_t)(n0 + nl) * D + dg * 8];
    __builtin_nontemporal_store(o0, (f32x4*)hp);
    __builtin_nontemporal_store(o1, (f32x4*)(hp + 4));

    unsigned int b0 = (unsigned int)f2bf(h2[0]) | ((unsigned int)f2bf(h2[1]) << 16);
    unsigned int b1 = (unsigned int)f2bf(h2[2]) | ((unsigned int)f2bf(h2[3]) << 16);
    unsigned int b2 = (unsigned int)f2bf(h2[4]) | ((unsigned int)f2bf(h2[5]) << 16);
    unsigned int b3 = (unsigned int)f2bf(h2[6]) | ((unsigned int)f2bf(h2[7]) << 16);
    *(uint4*)&h_bf[(size_t)(n0 + nl) * D + dg * 8] = make_uint4(b0, b1, b2, b3);
}

// ---------------------------------------------------------------- edge out
// Wave-autonomous, LDS-free, e-order, 2-stage software pipeline:
//   decode head -> prefetch NEXT head -> issue 8 h-gathers -> A-frag VALU
//   -> MFMAs -> epilogue (gather wait lands here) -> nt stores.
// col map: col = lr*8 + dt.
__global__ __launch_bounds__(256, 3) void edge_out_wave(
    const int* __restrict__ edge, const float* __restrict__ r,
    const float* __restrict__ W_erp, const float* __restrict__ b_erp,
    const unsigned short* __restrict__ h_bf, float* __restrict__ t)
{
    const int tid = threadIdx.x;
    const int w   = tid >> 6;
    const int l   = tid & 63;
    const int lr  = l & 15;
    const int lg  = l >> 4;

    bf16x8 wf[8][2];
    float bias[8];
#pragma unroll
    for (int dt = 0; dt < 8; ++dt) {
        const int col = lr * 8 + dt;
        bias[dt] = b_erp[col];
#pragma unroll
        for (int s = 0; s < 2; ++s) {
            bf16x8 v;
#pragma unroll
            for (int j = 0; j < 8; ++j) {
                const int k = s * 32 + lg * 8 + j;
                v[j] = (k < NRBF) ? (short)f2bf(W_erp[k * D + col]) : (short)0;
            }
            wf[dt][s] = v;
        }
    }

    const float start = expf(-RCUT);
    const float step  = (1.0f - start) / (NRBF - 1);
    const float bq    = (2.0f / NRBF) * (1.0f - start);
    const float beta  = 1.0f / (bq * bq);

    const int wid = blockIdx.x * 4 + w;
    const int nw  = gridDim.x * 4;
    const int ngroup = NE / 16;

    // prologue head
    int2 ep = make_int2(0, 0);
    float rv = 0.0f;
    if (wid < ngroup && l < 16) {
        ep = ((const int2*)edge)[wid * 16 + l];
        rv = r[wid * 16 + l];
    }

    for (int g = wid; g < ngroup; g += nw) {
        const int iv = ep.x;
        const int jv = ep.y;
        const float er = __expf(-rv);

        // prefetch next head
        int2 epn = make_int2(0, 0);
        float rvn = 0.0f;
        if (g + nw < ngroup && l < 16) {
            epn = ((const int2*)edge)[(g + nw) * 16 + l];
            rvn = r[(g + nw) * 16 + l];
        }

        const float erL = __shfl(er, lr);

        // issue the 8 random h gathers BEFORE the heavy VALU block
        bf16x8 hi0, hi1, hi2, hi3, hj0, hj1, hj2, hj3;
        {
            const int i0 = __shfl(iv, lg * 4 + 0), j0 = __shfl(jv, lg * 4 + 0);
            const int i1 = __shfl(iv, lg * 4 + 1), j1 = __shfl(jv, lg * 4 + 1);
            const int i2 = __shfl(iv, lg * 4 + 2), j2 = __shfl(jv, lg * 4 + 2);
            const int i3 = __shfl(iv, lg * 4 + 3), j3 = __shfl(jv, lg * 4 + 3);
            hi0 = *(const bf16x8*)(h_bf + (size_t)i0 * D + lr * 8);
            hj0 = *(const bf16x8*)(h_bf + (size_t)j0 * D + lr * 8);
            hi1 = *(const bf16x8*)(h_bf + (size_t)i1 * D + lr * 8);
            hj1 = *(const bf16x8*)(h_bf + (size_t)j1 * D + lr * 8);
            hi2 = *(const bf16x8*)(h_bf + (size_t)i2 * D + lr * 8);
            hj2 = *(const bf16x8*)(h_bf + (size_t)j2 * D + lr * 8);
            hi3 = *(const bf16x8*)(h_bf + (size_t)i3 * D + lr * 8);
            hj3 = *(const bf16x8*)(h_bf + (size_t)j3 * D + lr * 8);
        }

        // A-fragments (rbf, no c scaling in this kernel)
        bf16x8 af[2];
#pragma unroll
        for (int s = 0; s < 2; ++s) {
            bf16x8 a;
#pragma unroll
            for (int j = 0; j < 8; ++j) {
                const int k = s * 32 + lg * 8 + j;
                float pv = 0.0f;
                if (k < NRBF) {
                    const float diff = erL - (start + (float)k * step);
                    pv = __expf(-beta * diff * diff);
                }
                a[j] = (short)f2bf(pv);
            }
            af[s] = a;
        }

        f32x4 accs[8];
#pragma unroll
        for (int dt = 0; dt < 8; ++dt) {
            f32x4 acc = {0.0f, 0.0f, 0.0f, 0.0f};
            acc = __builtin_amdgcn_mfma_f32_16x16x32_bf16(af[0], wf[dt][0], acc, 0, 0, 0);
            acc = __builtin_amdgcn_mfma_f32_16x16x32_bf16(af[1], wf[dt][1], acc, 0, 0, 0);
            accs[dt] = acc;
        }

        const int eb = g * 16;
#pragma unroll
        for (int q = 0; q < 4; ++q) {
            const bf16x8 hi8 = (q == 0) ? hi0 : (q == 1) ? hi1 : (q == 2) ? hi2 : hi3;
            const bf16x8 hj8 = (q == 0) ? hj0 : (q == 1) ? hj1 : (q == 2) ? hj2 : hj3;
            float o[8];
#pragma unroll
            for (int dt = 0; dt < 8; ++dt) {
                const float hvf = bf2f((unsigned short)hi8[dt]) + bf2f((unsigned short)hj8[dt]);
                o[dt] = hvf * (accs[dt][q] + bias[dt]);
            }
            f32x4 o0 = {o[0], o[1], o[2], o[3]};
            f32x4 o1 = {o[4], o[5], o[6], o[7]};
            float* tp = &t[(size_t)(eb + lg * 4 + q) * D + lr * 8];
            __builtin_nontemporal_store(o0, (f32x4*)tp);
            __builtin_nontemporal_store(o1, (f32x4*)(tp + 4));
        }

        ep = epn;
        rv = rvn;
    }
}

// ---------------------------------------------------------------- launch
extern "C" void kernel_launch(void* const* d_in, const int* in_sizes, int n_in,
                              void* d_out, int out_size, void* d_ws, size_t ws_size,
                              hipStream_t stream) {
    const float* z      = (const float*)d_in[0];
    const int*   edge   = (const int*)d_in[1];
    const float* r      = (const float*)d_in[2];
    const float* u      = (const float*)d_in[3];
    const float* A_na_w  = (const float*)d_in[4];
    const float* A_na_b  = (const float*)d_in[5];
    const float* A_nbr_w = (const float*)d_in[6];
    const float* A_nbr_b = (const float*)d_in[7];
    const float* W_ndp_w = (const float*)d_in[8];
    const float* W_ndp_b = (const float*)d_in[9];
    const float* W_nrd_w = (const float*)d_in[10];
    const float* W_nrd_b = (const float*)d_in[11];
    const float* W_nru_w = (const float*)d_in[12];
    const float* W_nru_b = (const float*)d_in[13];
    const float* W_erp_w = (const float*)d_in[14];
    const float* W_erp_b = (const float*)d_in[15];
    const float* ln_g    = (const float*)d_in[16];
    const float* ln_b    = (const float*)d_in[17];

    float* out = (float*)d_out;
    float* h_out   = out;
    float* t_out   = out + (size_t)NN * D;
    float* rt0_out = t_out + (size_t)NE * D;
    float* rt1_out = rt0_out + (size_t)NE;
    float* rt2_out = rt1_out + (size_t)NE * 3;
    float* c_out   = rt2_out + (size_t)NE * 5;

    // ws: nbr_bf (12.8MB) | m f32 (25.6MB) | h_bf (12.8MB)
    unsigned short* nbr_bf = (unsigned short*)d_ws;
    float* m_ws   = (float*)((char*)d_ws + (size_t)NN * D * sizeof(unsigned short));
    unsigned short* h_bf = (unsigned short*)((char*)m_ws + (size_t)NN * D * sizeof(float));

    // CSR scratch in the t region (819MB): consumed by gather_msg, which
    // finishes before edge_out overwrites t (stream order).
    uint2* jr   = (uint2*)t_out;                 // NE uint2 (12.8 MB)
    int* off    = (int*)(jr + NE);               // NN+1
    int* cursor = off + (NN + 1);                // NN
    int* bsum   = cursor + NN;                   // 256

    hipMemsetAsync(cursor, 0, (size_t)NN * sizeof(int), stream);

    nbr_kernel<<<NN, 128, 0, stream>>>(z, A_nbr_w, A_nbr_b, nbr_bf);

    aux_kernel<<<(NE + 255) / 256, 256, 0, stream>>>(
        edge, r, u, rt0_out, rt1_out, rt2_out, c_out, cursor);

    scan1_kernel<<<SCAN_B, 256, 0, stream>>>(cursor, off, bsum);
    scan2_kernel<<<1, 256, 0, stream>>>(bsum);
    scan3_kernel<<<SCAN_B, 256, 0, stream>>>(off, bsum);

    hipMemsetAsync(cursor, 0, (size_t)NN * sizeof(int), stream);

    scatter_kernel<<<(NE + 255) / 256, 256, 0, stream>>>(edge, r, off, cursor, jr);

    {
        const int nwaves = (NN + NPW - 1) / NPW;          // 6250
        const int blocks = (nwaves + 3) / 4;              // 1563
        gather_msg_wave<<<blocks, 256, 0, stream>>>(
            jr, off, W_ndp_w, W_ndp_b, nbr_bf, m_ws);
    }

    node_kernel2<<<NN / NB, 256, 0, stream>>>(
        z, A_na_w, A_na_b, m_ws, W_nrd_w, W_nrd_b,
        W_nru_w, W_nru_b, ln_g, ln_b, h_out, h_bf);

    edge_out_wave<<<EO_GRID, 256, 0, stream>>>(
        edge, r, W_erp_w, W_erp_b, h_bf, t_out);
}